// Round 3
// baseline (58.689 us; speedup 1.0000x reference)
//
#include <hip/hip_runtime.h>
#include <math.h>

// Weighted partial cross-entropy, MI355X — fused sparse pipeline.
// Per block: compact labeled pixels of a 4096-pixel window into LDS, then
// immediately gather the 19 strided logits per labeled pixel (logsumexp),
// accumulate per-class {sum nll, count} in LDS, flush via global atomics.
// Finalize kernel computes inverse-frequency weights + scalar loss.

constexpr int C      = 19;
constexpr int HWp    = 512 * 512;      // 2^18 pixels per image
constexpr int LOG2HW = 18;
constexpr int NPIX   = 16 * HWp;       // 4,194,304 = 2^22 (idx fits 22 bits)
constexpr int WPIX   = 4096;           // pixels per block window
constexpr int ABLK   = NPIX / WPIX;    // 1024 blocks (4 per CU)
constexpr int ITERS  = WPIX / 4 / 256; // 4 vec4 iterations per thread

__global__ __launch_bounds__(256) void wpce_fused(
        const float* __restrict__ pred,
        const int4* __restrict__ tgt4, const float4* __restrict__ msk4,
        float* __restrict__ ws) {
    __shared__ unsigned ent[WPIX];     // worst-case: every pixel labeled (16KB)
    __shared__ int sCnt;
    __shared__ float sS[C], sCt[C];
    const int tid = threadIdx.x;
    if (tid == 0) sCnt = 0;
    if (tid < C) { sS[tid] = 0.f; sCt[tid] = 0.f; }
    __syncthreads();

    // ---- compact this block's window (coalesced 16B streams) ----
    const int base_v = blockIdx.x * (WPIX / 4);
#pragma unroll
    for (int it = 0; it < ITERS; ++it) {
        const int v = base_v + it * 256 + tid;
        const int4   t = tgt4[v];
        const float4 m = msk4[v];
        const unsigned i0 = (unsigned)v * 4u;
        if (m.x != 0.f) ent[atomicAdd(&sCnt, 1)] = (i0    ) | ((unsigned)t.x << 22);
        if (m.y != 0.f) ent[atomicAdd(&sCnt, 1)] = (i0 + 1) | ((unsigned)t.y << 22);
        if (m.z != 0.f) ent[atomicAdd(&sCnt, 1)] = (i0 + 2) | ((unsigned)t.z << 22);
        if (m.w != 0.f) ent[atomicAdd(&sCnt, 1)] = (i0 + 3) | ((unsigned)t.w << 22);
    }
    __syncthreads();

    // ---- gather + logsumexp for each labeled pixel ----
    const int n = sCnt;
    for (int j = tid; j < n; j += 256) {
        const unsigned e = ent[j];
        const int idx = (int)(e & 0x3FFFFFu);
        const int t   = (int)(e >> 22);
        const float* p = pred + (((size_t)(idx >> LOG2HW) * C) << LOG2HW)
                              + (idx & (HWp - 1));
        float x[C];
        float mx = -3.4e38f, xt = 0.f;
#pragma unroll
        for (int c = 0; c < C; ++c) {          // 19 independent strided loads
            const float v = p[(size_t)c << LOG2HW];
            x[c] = v;
            mx = fmaxf(mx, v);
            xt = (c == t) ? v : xt;            // static indices only (no scratch)
        }
        float se = 0.f;
#pragma unroll
        for (int c = 0; c < C; ++c) se += __expf(x[c] - mx);
        const float nll = mx + __logf(se) - xt;
        atomicAdd(&sS[t], nll);
        atomicAdd(&sCt[t], 1.f);               // mask is exactly 1.0 when labeled
    }
    __syncthreads();

    // ---- per-class flush: 38 device atomics per block ----
    if (tid < C && (sS[tid] != 0.f || sCt[tid] != 0.f)) {
        atomicAdd(&ws[tid],     sS[tid]);
        atomicAdd(&ws[C + tid], sCt[tid]);
    }
}

__global__ void wpce_fin(const float* __restrict__ ws, float* __restrict__ out) {
    const int l = threadIdx.x;   // one wave
    float S   = (l < C) ? ws[l]     : 0.f;
    float cnt = (l < C) ? ws[C + l] : 0.f;

    float total = cnt;
    for (int o = 1; o < 64; o <<= 1) total += __shfl_xor(total, o);

    float w = (l < C) ? total / (cnt + 1e-6f) : 0.f;   // inverse frequency
    float sw = w;
    for (int o = 1; o < 64; o <<= 1) sw += __shfl_xor(sw, o);

    float loss = (l < C) ? (w / sw * (float)C) * S : 0.f;
    for (int o = 1; o < 64; o <<= 1) loss += __shfl_xor(loss, o);

    if (l == 0) out[0] = (total > 0.f) ? loss / total : 0.f;
}

extern "C" void kernel_launch(void* const* d_in, const int* in_sizes, int n_in,
                              void* d_out, int out_size, void* d_ws, size_t ws_size,
                              hipStream_t stream) {
    const float* pred = (const float*)d_in[0];
    const int*   tgt  = (const int*)  d_in[1];
    const float* msk  = (const float*)d_in[2];
    float* ws = (float*)d_ws;

    // atomics accumulate; ws poisoned 0xAA once -> zero the 38 floats each call
    hipMemsetAsync(d_ws, 0, 2 * C * sizeof(float), stream);

    wpce_fused<<<ABLK, 256, 0, stream>>>(pred, (const int4*)tgt,
                                         (const float4*)msk, ws);
    wpce_fin<<<1, 64, 0, stream>>>(ws, (float*)d_out);
}

// Round 4
// 55.460 us; speedup vs baseline: 1.0582x; 1.0582x over previous
//
#include <hip/hip_runtime.h>
#include <math.h>

// Weighted partial cross-entropy, MI355X — 2-dispatch sparse pipeline.
// K1 compact: per-block window -> private worklist region + count (no global
//             atomics, no memset); block 0 zeros the 38 accumulators + done.
// K2 gather:  block b processes window b's list; 19 strided loads, logsumexp,
//             per-class {sum nll, count}; LAST block finalizes (weights+loss).

constexpr int C      = 19;
constexpr int HWp    = 512 * 512;      // 2^18 pixels per image
constexpr int LOG2HW = 18;
constexpr int NPIX   = 16 * HWp;       // 4,194,304 = 2^22 (idx fits 22 bits)
constexpr int WPIX   = 4096;           // pixels per window
constexpr int ABLK   = NPIX / WPIX;    // 1024 blocks
constexpr int ITERS  = WPIX / 4 / 256; // 4 vec4 iters/thread

// d_ws layout: [0..151] ws floats (S[19], cnt[19]); [256] done int;
// [4096..8191] per-block counts (1024 ints); [16384..] worklist regions.
constexpr int OFF_DONE = 256;
constexpr int OFF_CNT  = 4096;
constexpr int OFF_LIST = 16384;

__global__ __launch_bounds__(256) void wpce_compact(
        const int4* __restrict__ tgt4, const float4* __restrict__ msk4,
        char* __restrict__ wsb, int capPerBlk) {
    __shared__ unsigned ent[WPIX];
    __shared__ int sCnt;
    const int tid = threadIdx.x;
    if (tid == 0) sCnt = 0;
    // zero accumulators + done flag for this call (gather runs next dispatch)
    if (blockIdx.x == 0) {
        if (tid < 2 * C) ((float*)wsb)[tid] = 0.f;
        if (tid == 0)    *(int*)(wsb + OFF_DONE) = 0;
    }
    __syncthreads();

    const int base_v = blockIdx.x * (WPIX / 4);
#pragma unroll
    for (int it = 0; it < ITERS; ++it) {
        const int v = base_v + it * 256 + tid;
        const int4   t = tgt4[v];
        const float4 m = msk4[v];
        const unsigned i0 = (unsigned)v * 4u;
        if (m.x != 0.f) ent[atomicAdd(&sCnt, 1)] = (i0    ) | ((unsigned)t.x << 22);
        if (m.y != 0.f) ent[atomicAdd(&sCnt, 1)] = (i0 + 1) | ((unsigned)t.y << 22);
        if (m.z != 0.f) ent[atomicAdd(&sCnt, 1)] = (i0 + 2) | ((unsigned)t.z << 22);
        if (m.w != 0.f) ent[atomicAdd(&sCnt, 1)] = (i0 + 3) | ((unsigned)t.w << 22);
    }
    __syncthreads();

    const int n = min(sCnt, capPerBlk);
    unsigned* list = (unsigned*)(wsb + OFF_LIST) + (size_t)blockIdx.x * capPerBlk;
    for (int i = tid; i < n; i += 256) list[i] = ent[i];   // coalesced flush
    if (tid == 0) ((int*)(wsb + OFF_CNT))[blockIdx.x] = n;
}

__global__ __launch_bounds__(256) void wpce_gather(
        const float* __restrict__ pred, char* __restrict__ wsb,
        float* __restrict__ out, int capPerBlk) {
    __shared__ float sS[C], sCt[C];
    __shared__ int isLast;
    const int tid = threadIdx.x;
    if (tid < C) { sS[tid] = 0.f; sCt[tid] = 0.f; }
    __syncthreads();

    float* ws = (float*)wsb;
    const int n = ((const int*)(wsb + OFF_CNT))[blockIdx.x];
    const unsigned* list = (const unsigned*)(wsb + OFF_LIST)
                           + (size_t)blockIdx.x * capPerBlk;
    for (int j = tid; j < n; j += 256) {
        const unsigned e = list[j];
        const int idx = (int)(e & 0x3FFFFFu);
        const int t   = (int)(e >> 22);
        const float* p = pred + (((size_t)(idx >> LOG2HW) * C) << LOG2HW)
                              + (idx & (HWp - 1));
        float x[C];
        float mx = -3.4e38f, xt = 0.f;
#pragma unroll
        for (int c = 0; c < C; ++c) {          // 19 independent strided loads
            const float v = p[(size_t)c << LOG2HW];
            x[c] = v;
            mx = fmaxf(mx, v);
            xt = (c == t) ? v : xt;            // static indices only (no scratch)
        }
        float se = 0.f;
#pragma unroll
        for (int c = 0; c < C; ++c) se += __expf(x[c] - mx);
        const float nll = mx + __logf(se) - xt;
        atomicAdd(&sS[t], nll);
        atomicAdd(&sCt[t], 1.f);               // mask is exactly 1.0 when labeled
    }
    __syncthreads();

    if (tid < C && (sS[tid] != 0.f || sCt[tid] != 0.f)) {
        atomicAdd(&ws[tid],     sS[tid]);
        atomicAdd(&ws[C + tid], sCt[tid]);
    }
    // __syncthreads lowers to s_waitcnt vmcnt(0) + s_barrier -> all this
    // block's global atomics are performed before the done-increment below.
    __syncthreads();
    if (tid == 0)
        isLast = (atomicAdd((int*)(wsb + OFF_DONE), 1) == ABLK - 1);
    __syncthreads();

    if (isLast && tid < 64) {                  // one wave finalizes
        const int l = tid;
        float S   = (l < C) ? __hip_atomic_load(&ws[l],     __ATOMIC_RELAXED,
                                  __HIP_MEMORY_SCOPE_AGENT) : 0.f;
        float cnt = (l < C) ? __hip_atomic_load(&ws[C + l], __ATOMIC_RELAXED,
                                  __HIP_MEMORY_SCOPE_AGENT) : 0.f;

        float total = cnt;
        for (int o = 1; o < 64; o <<= 1) total += __shfl_xor(total, o);

        float w = (l < C) ? total / (cnt + 1e-6f) : 0.f;   // inverse frequency
        float sw = w;
        for (int o = 1; o < 64; o <<= 1) sw += __shfl_xor(sw, o);

        float loss = (l < C) ? (w / sw * (float)C) * S : 0.f;
        for (int o = 1; o < 64; o <<= 1) loss += __shfl_xor(loss, o);

        if (l == 0) out[0] = (total > 0.f) ? loss / total : 0.f;
    }
}

extern "C" void kernel_launch(void* const* d_in, const int* in_sizes, int n_in,
                              void* d_out, int out_size, void* d_ws, size_t ws_size,
                              hipStream_t stream) {
    const float* pred = (const float*)d_in[0];
    const int*   tgt  = (const int*)  d_in[1];
    const float* msk  = (const float*)d_in[2];
    char* wsb = (char*)d_ws;

    // per-block worklist capacity from ws_size (Poisson(82) labeled/window;
    // cap>=512 is >40 sigma for this dataset)
    long capl = ((long)ws_size - OFF_LIST) / 4 / ABLK;
    int cap = (capl > WPIX) ? WPIX : (int)capl;

    wpce_compact<<<ABLK, 256, 0, stream>>>((const int4*)tgt, (const float4*)msk,
                                           wsb, cap);
    wpce_gather<<<ABLK, 256, 0, stream>>>(pred, wsb, (float*)d_out, cap);
}

// Round 5
// 48.820 us; speedup vs baseline: 1.2021x; 1.1360x over previous
//
#include <hip/hip_runtime.h>
#include <math.h>

// Weighted partial cross-entropy, MI355X — single fused kernel.
// Each block: stream its 8192-pixel window of targets+mask (coalesced vec4),
// ballot-compact labeled pixels into LDS (sorted order), then gather the 19
// strided logits per labeled pixel (logsumexp), accumulate per-class
// {sum nll, count} in LDS, flush via device atomics. Last block (done-flag)
// computes inverse-frequency weights + scalar loss. Fusion overlaps the
// 32MB t/m stream with the random gather (the only non-gather cost left).

constexpr int C      = 19;
constexpr int HWp    = 512 * 512;      // 2^18 pixels per image
constexpr int LOG2HW = 18;
constexpr int NPIX   = 16 * HWp;       // 4,194,304 = 2^22 (idx fits 22 bits)
constexpr int WPIX   = 8192;           // pixels per block window
constexpr int ABLK   = NPIX / WPIX;    // 512 blocks
constexpr int ITERS  = WPIX / 4 / 256; // 8 vec4 iters/thread
constexpr int ECAP   = 2048;           // entry cap (2% of 8192 ~= 164; +148 sigma)

constexpr int OFF_DONE = 256;          // d_ws byte offsets

__global__ __launch_bounds__(256) void wpce_fused(
        const float* __restrict__ pred,
        const int4* __restrict__ tgt4, const float4* __restrict__ msk4,
        char* __restrict__ wsb, float* __restrict__ out) {
    __shared__ unsigned ent[ECAP];     // 8KB
    __shared__ int sCnt, isLast;
    __shared__ float sS[C], sCt[C];
    const int tid  = threadIdx.x;
    const int lane = tid & 63;
    if (tid == 0) sCnt = 0;
    if (tid < C) { sS[tid] = 0.f; sCt[tid] = 0.f; }
    __syncthreads();

    // ---- stream + ballot-compact this block's window ----
    const int base_v = blockIdx.x * (WPIX / 4);
    const unsigned long long lmask_lt = ((unsigned long long)1 << lane) - 1;
#pragma unroll
    for (int it = 0; it < ITERS; ++it) {
        const int v = base_v + it * 256 + tid;
        const int4   t = tgt4[v];
        const float4 m = msk4[v];
        const unsigned i0 = (unsigned)v * 4u;
        const float mm[4] = {m.x, m.y, m.z, m.w};
        const int   tt[4] = {t.x, t.y, t.z, t.w};
#pragma unroll
        for (int k = 0; k < 4; ++k) {
            const bool lab = (mm[k] != 0.f);
            const unsigned long long b = __ballot(lab);
            if (b) {
                int base;
                if (lane == 0) base = atomicAdd(&sCnt, __popcll(b));
                base = __shfl(base, 0);
                if (lab) {
                    const int pos = base + __popcll(b & lmask_lt);
                    if (pos < ECAP)
                        ent[pos] = (i0 + k) | ((unsigned)tt[k] << 22);
                }
            }
        }
    }
    __syncthreads();

    // ---- gather + logsumexp per labeled pixel ----
    const int n = min(sCnt, ECAP);
    for (int j = tid; j < n; j += 256) {
        const unsigned e = ent[j];
        const int idx = (int)(e & 0x3FFFFFu);
        const int t   = (int)(e >> 22);
        const float* p = pred + (((size_t)(idx >> LOG2HW) * C) << LOG2HW)
                              + (idx & (HWp - 1));
        float x[C];
        float mx = -3.4e38f, xt = 0.f;
#pragma unroll
        for (int c = 0; c < C; ++c) {          // 19 independent strided loads
            const float v = p[(size_t)c << LOG2HW];
            x[c] = v;
            mx = fmaxf(mx, v);
            xt = (c == t) ? v : xt;            // static indices only (no scratch)
        }
        float se = 0.f;
#pragma unroll
        for (int c = 0; c < C; ++c) se += __expf(x[c] - mx);
        const float nll = mx + __logf(se) - xt;
        atomicAdd(&sS[t], nll);
        atomicAdd(&sCt[t], 1.f);               // mask is exactly 1.0 when labeled
    }
    __syncthreads();

    // ---- flush per-class partials (device-scope atomics) ----
    float* ws = (float*)wsb;
    if (tid < C && (sS[tid] != 0.f || sCt[tid] != 0.f)) {
        atomicAdd(&ws[tid],     sS[tid]);
        atomicAdd(&ws[C + tid], sCt[tid]);
    }
    // __syncthreads lowers to s_waitcnt vmcnt(0)+s_barrier: flush performed
    // before the done-increment below.
    __syncthreads();
    if (tid == 0)
        isLast = (atomicAdd((int*)(wsb + OFF_DONE), 1) == ABLK - 1);
    __syncthreads();

    // ---- last block finalizes: weights + scalar loss ----
    if (isLast && tid < 64) {
        const int l = tid;
        float S   = (l < C) ? __hip_atomic_load(&ws[l],     __ATOMIC_RELAXED,
                                  __HIP_MEMORY_SCOPE_AGENT) : 0.f;
        float cnt = (l < C) ? __hip_atomic_load(&ws[C + l], __ATOMIC_RELAXED,
                                  __HIP_MEMORY_SCOPE_AGENT) : 0.f;

        float total = cnt;
        for (int o = 1; o < 64; o <<= 1) total += __shfl_xor(total, o);

        float w = (l < C) ? total / (cnt + 1e-6f) : 0.f;   // inverse frequency
        float sw = w;
        for (int o = 1; o < 64; o <<= 1) sw += __shfl_xor(sw, o);

        float loss = (l < C) ? (w / sw * (float)C) * S : 0.f;
        for (int o = 1; o < 64; o <<= 1) loss += __shfl_xor(loss, o);

        if (l == 0) out[0] = (total > 0.f) ? loss / total : 0.f;
    }
}

extern "C" void kernel_launch(void* const* d_in, const int* in_sizes, int n_in,
                              void* d_out, int out_size, void* d_ws, size_t ws_size,
                              hipStream_t stream) {
    const float* pred = (const float*)d_in[0];
    const int*   tgt  = (const int*)  d_in[1];
    const float* msk  = (const float*)d_in[2];

    // zero {S[19], cnt[19]} accumulators + done flag (R2 vs R4: this fill and
    // its dispatch boundary measured free under graph replay)
    hipMemsetAsync(d_ws, 0, 512, stream);

    wpce_fused<<<ABLK, 256, 0, stream>>>(pred, (const int4*)tgt,
                                         (const float4*)msk,
                                         (char*)d_ws, (float*)d_out);
}

// Round 6
// 47.520 us; speedup vs baseline: 1.2350x; 1.0274x over previous
//
#include <hip/hip_runtime.h>
#include <math.h>

// Weighted partial cross-entropy, MI355X — fused, chunk-rotated pipeline.
// Each block owns an 8192-pixel window, processed as 4 chunks of 2048 px.
// Chunk order is rotated by blockIdx (ck + blk&3): at any instant ~1/4 of
// blocks stream targets+mask (coalesced) while ~3/4 do the scattered 19-plane
// gather -> stream traffic fills the DRAM slack of the row-miss-bound gather.
// Per chunk: ballot-compact labeled pixels into LDS (sorted), gather+logsumexp,
// accumulate per-class {sum nll, count} in LDS; flush once; last block
// (done-flag) computes inverse-frequency weights + scalar loss.

constexpr int C      = 19;
constexpr int HWp    = 512 * 512;      // 2^18 pixels per image
constexpr int LOG2HW = 18;
constexpr int NPIX   = 16 * HWp;       // 4,194,304 = 2^22 (idx fits 22 bits)
constexpr int WPIX   = 8192;           // pixels per block window
constexpr int ABLK   = NPIX / WPIX;    // 512 blocks
constexpr int CHUNK  = 2048;           // pixels per chunk
constexpr int NCHUNK = WPIX / CHUNK;   // 4
constexpr int CITERS = CHUNK / 4 / 256;// 2 vec4 iters/thread/chunk

constexpr int OFF_DONE = 256;          // d_ws byte offset of done counter

__global__ __launch_bounds__(256) void wpce_fused(
        const float* __restrict__ pred,
        const int4* __restrict__ tgt4, const float4* __restrict__ msk4,
        char* __restrict__ wsb, float* __restrict__ out) {
    __shared__ unsigned ent[CHUNK];    // worst-case whole chunk labeled (8KB)
    __shared__ int sCnt, isLast;
    __shared__ float sS[C], sCt[C];
    const int tid  = threadIdx.x;
    const int lane = tid & 63;
    if (tid < C) { sS[tid] = 0.f; sCt[tid] = 0.f; }
    const unsigned long long lmask_lt = ((unsigned long long)1 << lane) - 1;
    const int rot = blockIdx.x & (NCHUNK - 1);

    for (int ck = 0; ck < NCHUNK; ++ck) {
        const int cs = (ck + rot) & (NCHUNK - 1);   // rotated chunk order
        if (tid == 0) sCnt = 0;
        __syncthreads();               // reset visible (prev gather done: loop-end barrier)

        // ---- stream + ballot-compact this chunk (coalesced 16B loads) ----
        const int base_v = blockIdx.x * (WPIX / 4) + cs * (CHUNK / 4);
#pragma unroll
        for (int it = 0; it < CITERS; ++it) {
            const int v = base_v + it * 256 + tid;
            const int4   t = tgt4[v];
            const float4 m = msk4[v];
            const unsigned i0 = (unsigned)v * 4u;
            const float mm[4] = {m.x, m.y, m.z, m.w};
            const int   tt[4] = {t.x, t.y, t.z, t.w};
#pragma unroll
            for (int k = 0; k < 4; ++k) {
                const bool lab = (mm[k] != 0.f);
                const unsigned long long b = __ballot(lab);
                if (b) {
                    int base;
                    if (lane == 0) base = atomicAdd(&sCnt, __popcll(b));
                    base = __shfl(base, 0);
                    if (lab)       // ent[] can hold a fully-labeled chunk: no cap
                        ent[base + __popcll(b & lmask_lt)] =
                            (i0 + k) | ((unsigned)tt[k] << 22);
                }
            }
        }
        __syncthreads();

        // ---- gather + logsumexp per labeled pixel of this chunk ----
        const int n = sCnt;
        for (int j = tid; j < n; j += 256) {
            const unsigned e = ent[j];
            const int idx = (int)(e & 0x3FFFFFu);
            const int t   = (int)(e >> 22);
            const float* p = pred + (((size_t)(idx >> LOG2HW) * C) << LOG2HW)
                                  + (idx & (HWp - 1));
            float x[C];
            float mx = -3.4e38f, xt = 0.f;
#pragma unroll
            for (int c = 0; c < C; ++c) {      // 19 independent strided loads
                const float v = p[(size_t)c << LOG2HW];
                x[c] = v;
                mx = fmaxf(mx, v);
                xt = (c == t) ? v : xt;        // static indices only (no scratch)
            }
            float se = 0.f;
#pragma unroll
            for (int c = 0; c < C; ++c) se += __expf(x[c] - mx);
            const float nll = mx + __logf(se) - xt;
            atomicAdd(&sS[t], nll);
            atomicAdd(&sCt[t], 1.f);           // mask is exactly 1.0 when labeled
        }
        __syncthreads();               // gathers done before next chunk's reset
    }

    // ---- flush per-class partials (device-scope atomics) ----
    float* ws = (float*)wsb;
    if (tid < C && (sS[tid] != 0.f || sCt[tid] != 0.f)) {
        atomicAdd(&ws[tid],     sS[tid]);
        atomicAdd(&ws[C + tid], sCt[tid]);
    }
    // __syncthreads lowers to s_waitcnt vmcnt(0)+s_barrier: flush performed
    // before the done-increment below.
    __syncthreads();
    if (tid == 0)
        isLast = (atomicAdd((int*)(wsb + OFF_DONE), 1) == ABLK - 1);
    __syncthreads();

    // ---- last block finalizes: weights + scalar loss ----
    if (isLast && tid < 64) {
        const int l = tid;
        float S   = (l < C) ? __hip_atomic_load(&ws[l],     __ATOMIC_RELAXED,
                                  __HIP_MEMORY_SCOPE_AGENT) : 0.f;
        float cnt = (l < C) ? __hip_atomic_load(&ws[C + l], __ATOMIC_RELAXED,
                                  __HIP_MEMORY_SCOPE_AGENT) : 0.f;

        float total = cnt;
        for (int o = 1; o < 64; o <<= 1) total += __shfl_xor(total, o);

        float w = (l < C) ? total / (cnt + 1e-6f) : 0.f;   // inverse frequency
        float sw = w;
        for (int o = 1; o < 64; o <<= 1) sw += __shfl_xor(sw, o);

        float loss = (l < C) ? (w / sw * (float)C) * S : 0.f;
        for (int o = 1; o < 64; o <<= 1) loss += __shfl_xor(loss, o);

        if (l == 0) out[0] = (total > 0.f) ? loss / total : 0.f;
    }
}

extern "C" void kernel_launch(void* const* d_in, const int* in_sizes, int n_in,
                              void* d_out, int out_size, void* d_ws, size_t ws_size,
                              hipStream_t stream) {
    const float* pred = (const float*)d_in[0];
    const int*   tgt  = (const int*)  d_in[1];
    const float* msk  = (const float*)d_in[2];

    // zero {S[19], cnt[19]} accumulators + done flag (measured free: R2 vs R4)
    hipMemsetAsync(d_ws, 0, 512, stream);

    wpce_fused<<<ABLK, 256, 0, stream>>>(pred, (const int4*)tgt,
                                         (const float4*)msk,
                                         (char*)d_ws, (float*)d_out);
}